// Round 6
// baseline (46979.880 us; speedup 1.0000x reference)
//
#include <hip/hip_runtime.h>
#include <hip/hip_cooperative_groups.h>
#include <hip/hip_fp16.h>
#include <math.h>

namespace cg = cooperative_groups;

#define H      4096
#define SEQ    2048
#define HOR    64
#define NBLK   256
#define NTHR   512
#define NWAVE  (NTHR / 64)
#define RPW    2            // rows per wave; 8 waves * 2 = 16 rows per block
#define J      16           // float4 chunks per lane per row: H/(64*4)
#define NELEM  (NWAVE * RPW)     // 16 h-elements per block
#define TOTAL  (SEQ + HOR)       // 2112 steps

#define SMEM_H     (H * 4)               // 16384 B: h vector (fp32)
#define SMEM_R     (NELEM * H * 2)       // 131072 B: r_Wh rows (fp16)
#define SMEM_RED   64
#define SMEM_BYTES (SMEM_H + SMEM_R + SMEM_RED)

// LLVM inline-asm accepts ext_vector types (true LLVM vectors) in "v"
// constraints for BOTH inputs and outputs; 128-bit aggregates (uint4 struct)
// fail as inputs ("indirect register inputs").
typedef unsigned int u32x4 __attribute__((ext_vector_type(4)));

// ---- fence-free L3-coherent ops (sc0 sc1 = bypass L1+L2; Infinity Cache is
// memory-side and coherent across XCDs). Never emits buffer_inv/wb. ----
__device__ __forceinline__ u32x4 load_l3_u4(const u32x4* p) {
    u32x4 v;
    asm volatile("global_load_dwordx4 %0, %1, off sc0 sc1"
                 : "=v"(v) : "v"(p) : "memory");
    return v;
}
__device__ __forceinline__ void store_l3_u4(u32x4* p, u32x4 v) {
    asm volatile("global_store_dwordx4 %0, %1, off sc0 sc1"
                 :: "v"(p), "v"(v) : "memory");
}
__device__ __forceinline__ void vm_drain() {
    asm volatile("s_waitcnt vmcnt(0)" ::: "memory");
}

__device__ __forceinline__ float wave_reduce(float v) {
#pragma unroll
    for (int o = 32; o > 0; o >>= 1) v += __shfl_xor(v, o, 64);
    return v;
}

__device__ __forceinline__ float dot4(float4 a, float4 b) {
    float s = a.x * b.x;
    s = fmaf(a.y, b.y, s);
    s = fmaf(a.z, b.z, s);
    s = fmaf(a.w, b.w, s);
    return s;
}

union H4U { uint2 u; __half h[4]; };

__device__ __forceinline__ uint2 pack4(float4 v) {
    H4U c;
    c.h[0] = __float2half_rn(v.x); c.h[1] = __float2half_rn(v.y);
    c.h[2] = __float2half_rn(v.z); c.h[3] = __float2half_rn(v.w);
    return c.u;
}

__device__ __forceinline__ float4 unpack4(uint2 p) {
    H4U c; c.u = p;
    return make_float4(__half2float(c.h[0]), __half2float(c.h[1]),
                       __half2float(c.h[2]), __half2float(c.h[3]));
}

// Fully weight-resident persistent GRU with FLAG-IN-DATA dataflow exchange.
// h is published as {f32 value, u32 step-tag} 8B packets; consumers poll the
// tagged data directly (no flags, no fences, no separate store-drain on the
// critical path). buf[t&1] holds H[t] tagged t; max inter-block skew is 1
// step (a block writes H[t+1] only after confirming ALL of H[t]), so the
// 2-buffer ping-pong is race-free. 0xAA poison never equals a tag.
__global__ __launch_bounds__(NTHR, 2) void gru_kernel(
    const float* __restrict__ xseq,
    const float* __restrict__ uWx, const float* __restrict__ uWh, const float* __restrict__ ubv,
    const float* __restrict__ rWx, const float* __restrict__ rWh, const float* __restrict__ rbv,
    const float* __restrict__ wxv, const float* __restrict__ Whm, const float* __restrict__ bbv,
    const float* __restrict__ Vv,  const float* __restrict__ cv,
    float* __restrict__ out, float* __restrict__ ws)
{
    cg::grid_group grid = cg::this_grid();
    extern __shared__ unsigned char smem[];
    float* hF  = (float*)smem;                         // h, 4096 fp32
    uint2* rW  = (uint2*)(smem + SMEM_H);              // r_Wh fp16
    float* red = (float*)(smem + SMEM_H + SMEM_R);     // NWAVE partials

    const int tid  = threadIdx.x;
    const int wv   = tid >> 6;
    const int lane = tid & 63;
    const int bid  = blockIdx.x;
    const int r0   = bid * NELEM + wv * RPW;
    const int r1   = r0 + 1;

    // tagged h buffers: 2 x 4096 x {val,tag} = 2 x 2048 u32x4
    u32x4* hbuf0 = (u32x4*)ws;
    u32x4* hbuf1 = hbuf0 + (H / 2);

    // ---- one-time load: pin weights on-chip ----
    const float4* w0p = (const float4*)(Whm + (size_t)r0 * H);
    const float4* w1p = (const float4*)(Whm + (size_t)r1 * H);
    const float4* u0p = (const float4*)(uWh + (size_t)r0 * H);
    const float4* u1p = (const float4*)(uWh + (size_t)r1 * H);
    const float4* p0p = (const float4*)(rWh + (size_t)r0 * H);
    const float4* p1p = (const float4*)(rWh + (size_t)r1 * H);

    float4 wA[J], wB[J];
    uint2  uA[J], uB[J];
    uint2* rs0 = rW + (wv * RPW + 0) * (H / 4);
    uint2* rs1 = rW + (wv * RPW + 1) * (H / 4);

#pragma unroll
    for (int j = 0; j < J; ++j) {
        const int idx = j * 64 + lane;
        wA[j] = w0p[idx];
        wB[j] = w1p[idx];
        uA[j] = pack4(u0p[idx]);
        uB[j] = pack4(u1p[idx]);
        rs0[idx] = pack4(p0p[idx]);
        rs1[idx] = pack4(p1p[idx]);
    }
#pragma unroll
    for (int j = 0; j < J; ++j) {
        asm volatile("" : "+v"(wA[j].x), "+v"(wA[j].y), "+v"(wA[j].z), "+v"(wA[j].w));
        asm volatile("" : "+v"(wB[j].x), "+v"(wB[j].y), "+v"(wB[j].z), "+v"(wB[j].w));
        asm volatile("" : "+v"(uA[j].x), "+v"(uA[j].y));
        asm volatile("" : "+v"(uB[j].x), "+v"(uB[j].y));
    }

    const float uwx0 = uWx[r0], uwx1 = uWx[r1], ub0 = ubv[r0], ub1 = ubv[r1];
    const float rwx0 = rWx[r0], rwx1 = rWx[r1], rb0 = rbv[r0], rb1 = rbv[r1];
    const float wx0  = wxv[r0], wx1  = wxv[r1], bb0 = bbv[r0], bb1 = bbv[r1];
    const float c0 = cv[0];

    // H[0] = 0 tagged 0: each block publishes its own 8 packets of buf0.
    if (tid < NELEM / 2) {
        u32x4 z; z.x = 0u; z.y = 0u; z.z = 0u; z.w = 0u;
        store_l3_u4(&hbuf0[bid * (NELEM / 2) + tid], z);
    }

    grid.sync();   // one-time; dataflow handles everything afterwards

    const float4* v4g = (const float4*)Vv;
    float2* hF2 = (float2*)hF;

#pragma unroll 1
    for (int t = 0; t < TOTAL; ++t) {
        const u32x4* src = (t & 1) ? hbuf1 : hbuf0;   // H[t] tagged t
        u32x4*       dst = (t & 1) ? hbuf0 : hbuf1;   // H[t+1] tagged t+1
        const unsigned tag = (unsigned)t;

        // ---- data-poll: 8 elements/thread as 4 x dwordx4; commit on tag match ----
        {
            unsigned done = 0;
            u32x4 t0, t1, t2, t3;
            do {
                if (!(done & 1u)) t0 = load_l3_u4(&src[0 * NTHR + tid]);
                if (!(done & 2u)) t1 = load_l3_u4(&src[1 * NTHR + tid]);
                if (!(done & 4u)) t2 = load_l3_u4(&src[2 * NTHR + tid]);
                if (!(done & 8u)) t3 = load_l3_u4(&src[3 * NTHR + tid]);
                vm_drain();
                if (!(done & 1u) && t0.y == tag && t0.w == tag) {
                    hF2[0 * NTHR + tid] = make_float2(__uint_as_float(t0.x), __uint_as_float(t0.z));
                    done |= 1u;
                }
                if (!(done & 2u) && t1.y == tag && t1.w == tag) {
                    hF2[1 * NTHR + tid] = make_float2(__uint_as_float(t1.x), __uint_as_float(t1.z));
                    done |= 2u;
                }
                if (!(done & 4u) && t2.y == tag && t2.w == tag) {
                    hF2[2 * NTHR + tid] = make_float2(__uint_as_float(t2.x), __uint_as_float(t2.z));
                    done |= 4u;
                }
                if (!(done & 8u) && t3.y == tag && t3.w == tag) {
                    hF2[3 * NTHR + tid] = make_float2(__uint_as_float(t3.x), __uint_as_float(t3.z));
                    done |= 8u;
                }
            } while (done != 15u);
        }
        __syncthreads();   // hF fully staged

        float x;
        if (t < SEQ) {
            x = xseq[t];
        } else {
            // y = v.h + c0, redundantly and identically in every block
            float4 a0 = ((const float4*)hF)[tid];
            float4 a1 = ((const float4*)hF)[tid + NTHR];
            float p = dot4(a0, v4g[tid]) + dot4(a1, v4g[tid + NTHR]);
            p = wave_reduce(p);
            if (lane == 0) red[wv] = p;
            __syncthreads();
            float y = c0;
#pragma unroll
            for (int w = 0; w < NWAVE; ++w) y += red[w];
            x = y;
            if (t > SEQ && bid == 0 && tid == 0) out[t - SEQ - 1] = y;
        }

        // ---- six resident row-dots against LDS h ----
        float au0 = 0.f, au1 = 0.f, ar0 = 0.f, ar1 = 0.f, aw0 = 0.f, aw1 = 0.f;
#pragma unroll
        for (int j = 0; j < J; ++j) {
            const int idx = j * 64 + lane;
            const float4 hv = ((const float4*)hF)[idx];
            aw0 = fmaf(wA[j].x, hv.x, aw0); aw0 = fmaf(wA[j].y, hv.y, aw0);
            aw0 = fmaf(wA[j].z, hv.z, aw0); aw0 = fmaf(wA[j].w, hv.w, aw0);
            aw1 = fmaf(wB[j].x, hv.x, aw1); aw1 = fmaf(wB[j].y, hv.y, aw1);
            aw1 = fmaf(wB[j].z, hv.z, aw1); aw1 = fmaf(wB[j].w, hv.w, aw1);
            const float4 ua = unpack4(uA[j]);
            au0 = fmaf(ua.x, hv.x, au0); au0 = fmaf(ua.y, hv.y, au0);
            au0 = fmaf(ua.z, hv.z, au0); au0 = fmaf(ua.w, hv.w, au0);
            const float4 ub = unpack4(uB[j]);
            au1 = fmaf(ub.x, hv.x, au1); au1 = fmaf(ub.y, hv.y, au1);
            au1 = fmaf(ub.z, hv.z, au1); au1 = fmaf(ub.w, hv.w, au1);
            const float4 ra = unpack4(rs0[idx]);
            ar0 = fmaf(ra.x, hv.x, ar0); ar0 = fmaf(ra.y, hv.y, ar0);
            ar0 = fmaf(ra.z, hv.z, ar0); ar0 = fmaf(ra.w, hv.w, ar0);
            const float4 rb = unpack4(rs1[idx]);
            ar1 = fmaf(rb.x, hv.x, ar1); ar1 = fmaf(rb.y, hv.y, ar1);
            ar1 = fmaf(rb.z, hv.z, ar1); ar1 = fmaf(rb.w, hv.w, ar1);
        }
        au0 = wave_reduce(au0); au1 = wave_reduce(au1);
        ar0 = wave_reduce(ar0); ar1 = wave_reduce(ar1);
        aw0 = wave_reduce(aw0); aw1 = wave_reduce(aw1);

        if (lane == 0) {
            const float ho0 = hF[r0], ho1 = hF[r1];
            const float zu0 = fmaf(uwx0, x, au0 + ub0);
            const float zr0 = fmaf(rwx0, x, ar0 + rb0);
            const float u0  = 1.f / (1.f + expf(-zu0));
            const float g0  = 1.f / (1.f + expf(-zr0));
            const float hh0 = tanhf(fmaf(wx0, x, fmaf(g0, aw0, bb0)));
            const float hn0 = fmaf(u0, hh0 - ho0, ho0);
            const float zu1 = fmaf(uwx1, x, au1 + ub1);
            const float zr1 = fmaf(rwx1, x, ar1 + rb1);
            const float u1  = 1.f / (1.f + expf(-zu1));
            const float g1  = 1.f / (1.f + expf(-zr1));
            const float hh1 = tanhf(fmaf(wx1, x, fmaf(g1, aw1, bb1)));
            const float hn1 = fmaf(u1, hh1 - ho1, ho1);
            // publish both rows + tag in ONE 16B packet (r0 is even)
            u32x4 pkt;
            pkt.x = __float_as_uint(hn0); pkt.y = tag + 1u;
            pkt.z = __float_as_uint(hn1); pkt.w = tag + 1u;
            store_l3_u4(&dst[r0 >> 1], pkt);
        }
        // protect hF: no thread may start re-staging (next t) until all waves
        // finished consuming this step's hF.
        __syncthreads();
    }

    // preds[63] from H[TOTAL] (TOTAL even -> buf0), tag == TOTAL; block 0 only.
    if (bid == 0) {
        const unsigned tag = (unsigned)TOTAL;
        unsigned done = 0;
        u32x4 t0, t1, t2, t3;
        do {
            if (!(done & 1u)) t0 = load_l3_u4(&hbuf0[0 * NTHR + tid]);
            if (!(done & 2u)) t1 = load_l3_u4(&hbuf0[1 * NTHR + tid]);
            if (!(done & 4u)) t2 = load_l3_u4(&hbuf0[2 * NTHR + tid]);
            if (!(done & 8u)) t3 = load_l3_u4(&hbuf0[3 * NTHR + tid]);
            vm_drain();
            if (!(done & 1u) && t0.y == tag && t0.w == tag) {
                hF2[0 * NTHR + tid] = make_float2(__uint_as_float(t0.x), __uint_as_float(t0.z));
                done |= 1u;
            }
            if (!(done & 2u) && t1.y == tag && t1.w == tag) {
                hF2[1 * NTHR + tid] = make_float2(__uint_as_float(t1.x), __uint_as_float(t1.z));
                done |= 2u;
            }
            if (!(done & 4u) && t2.y == tag && t2.w == tag) {
                hF2[2 * NTHR + tid] = make_float2(__uint_as_float(t2.x), __uint_as_float(t2.z));
                done |= 4u;
            }
            if (!(done & 8u) && t3.y == tag && t3.w == tag) {
                hF2[3 * NTHR + tid] = make_float2(__uint_as_float(t3.x), __uint_as_float(t3.z));
                done |= 8u;
            }
        } while (done != 15u);
        __syncthreads();
        float4 a0 = ((const float4*)hF)[tid];
        float4 a1 = ((const float4*)hF)[tid + NTHR];
        float p = dot4(a0, v4g[tid]) + dot4(a1, v4g[tid + NTHR]);
        p = wave_reduce(p);
        if (lane == 0) red[wv] = p;
        __syncthreads();
        if (tid == 0) {
            float y = c0;
            for (int w = 0; w < NWAVE; ++w) y += red[w];
            out[HOR - 1] = y;
        }
    }
}

extern "C" void kernel_launch(void* const* d_in, const int* in_sizes, int n_in,
                              void* d_out, int out_size, void* d_ws, size_t ws_size,
                              hipStream_t stream) {
    const float* xseq = (const float*)d_in[0];
    const float* uWx  = (const float*)d_in[2];
    const float* uWh  = (const float*)d_in[3];
    const float* ubv  = (const float*)d_in[4];
    const float* rWx  = (const float*)d_in[5];
    const float* rWh  = (const float*)d_in[6];
    const float* rbv  = (const float*)d_in[7];
    const float* wxv  = (const float*)d_in[8];
    const float* Whm  = (const float*)d_in[9];
    const float* bbv  = (const float*)d_in[10];
    const float* Vv   = (const float*)d_in[11];
    const float* cv   = (const float*)d_in[12];
    float* out = (float*)d_out;
    float* ws  = (float*)d_ws;

    (void)hipFuncSetAttribute((const void*)gru_kernel,
                        hipFuncAttributeMaxDynamicSharedMemorySize, SMEM_BYTES);

    void* args[] = { &xseq, &uWx, &uWh, &ubv, &rWx, &rWh, &rbv,
                     &wxv, &Whm, &bbv, &Vv, &cv, &out, &ws };
    (void)hipLaunchCooperativeKernel((void*)gru_kernel, dim3(NBLK), dim3(NTHR),
                               args, SMEM_BYTES, stream);
}

// Round 7
// 34435.669 us; speedup vs baseline: 1.3643x; 1.3643x over previous
//
#include <hip/hip_runtime.h>
#include <hip/hip_cooperative_groups.h>
#include <hip/hip_fp16.h>
#include <math.h>

namespace cg = cooperative_groups;

#define H      4096
#define SEQ    2048
#define HOR    64
#define NBLK   256
#define NTHR   512
#define NWAVE  (NTHR / 64)
#define RPW    2            // rows per wave; 8 waves * 2 = 16 rows per block
#define J      16           // float4 chunks per lane per row: H/(64*4)
#define NELEM  (NWAVE * RPW)     // 16 h-elements per block
#define TOTAL  (SEQ + HOR)       // 2112 steps

#define SMEM_H     (H * 4)               // 16384 B: h vector (fp32)
#define SMEM_R     (NELEM * H * 2)       // 131072 B: r_Wh rows (fp16)
#define SMEM_RED   64
#define SMEM_BYTES (SMEM_H + SMEM_R + SMEM_RED)

#define AGENT __HIP_MEMORY_SCOPE_AGENT

// ---- fence-free L3-coherent ops (sc0 sc1 = bypass L1+L2; Infinity Cache is
// memory-side and coherent across XCDs). Never emits buffer_inv/wb. ----
__device__ __forceinline__ void store_l3_f32(float* p, float v) {
    asm volatile("global_store_dword %0, %1, off sc0 sc1"
                 :: "v"(p), "v"(v) : "memory");
}
__device__ __forceinline__ void store_l3_u32(unsigned* p, unsigned v) {
    asm volatile("global_store_dword %0, %1, off sc0 sc1"
                 :: "v"(p), "v"(v) : "memory");
}
__device__ __forceinline__ unsigned load_l3_u32(const unsigned* p) {
    unsigned v;
    asm volatile("global_load_dword %0, %1, off sc0 sc1\n\t"
                 "s_waitcnt vmcnt(0)"
                 : "=v"(v) : "v"(p) : "memory");
    return v;
}
__device__ __forceinline__ float4 load_l3_f4(const float4* p) {
    float4 v;
    asm volatile("global_load_dwordx4 %0, %1, off sc0 sc1"
                 : "=v"(v) : "v"(p) : "memory");
    return v;
}
__device__ __forceinline__ void vm_drain() {
    asm volatile("s_waitcnt vmcnt(0)" ::: "memory");
}

__device__ __forceinline__ float wave_reduce(float v) {
#pragma unroll
    for (int o = 32; o > 0; o >>= 1) v += __shfl_xor(v, o, 64);
    return v;
}

__device__ __forceinline__ float dot4(float4 a, float4 b) {
    float s = a.x * b.x;
    s = fmaf(a.y, b.y, s);
    s = fmaf(a.z, b.z, s);
    s = fmaf(a.w, b.w, s);
    return s;
}

union H4U { uint2 u; __half h[4]; };

__device__ __forceinline__ uint2 pack4(float4 v) {
    H4U c;
    c.h[0] = __float2half_rn(v.x); c.h[1] = __float2half_rn(v.y);
    c.h[2] = __float2half_rn(v.z); c.h[3] = __float2half_rn(v.w);
    return c.u;
}

__device__ __forceinline__ float4 unpack4(uint2 p) {
    H4U c; c.u = p;
    return make_float4(__half2float(c.h[0]), __half2float(c.h[1]),
                       __half2float(c.h[2]), __half2float(c.h[3]));
}

// Fully weight-resident persistent GRU with single-counter grid barrier.
// Arrival: each block fire-and-forgets ONE relaxed agent-scope atomicAdd to a
// monotonic counter (after draining its sc0sc1 h-stores). Wait: ONE thread per
// block polls the counter with backoff. Poll traffic: 256 same-line loads per
// ~0.3us (vs r4's 65k pollers on 16 lines, vs r6's 131k x 64B whole-buffer
// spin that congested the fabric).
__global__ __launch_bounds__(NTHR, 2) void gru_kernel(
    const float* __restrict__ xseq,
    const float* __restrict__ uWx, const float* __restrict__ uWh, const float* __restrict__ ubv,
    const float* __restrict__ rWx, const float* __restrict__ rWh, const float* __restrict__ rbv,
    const float* __restrict__ wxv, const float* __restrict__ Whm, const float* __restrict__ bbv,
    const float* __restrict__ Vv,  const float* __restrict__ cv,
    float* __restrict__ out, float* __restrict__ ws)
{
    cg::grid_group grid = cg::this_grid();
    extern __shared__ unsigned char smem[];
    float* hF  = (float*)smem;                         // h, 4096 fp32
    uint2* rW  = (uint2*)(smem + SMEM_H);              // r_Wh fp16
    float* red = (float*)(smem + SMEM_H + SMEM_R);     // NWAVE partials

    const int tid  = threadIdx.x;
    const int wv   = tid >> 6;
    const int lane = tid & 63;
    const int bid  = blockIdx.x;
    const int r0   = bid * NELEM + wv * RPW;
    const int r1   = r0 + 1;

    float*    hA  = ws;
    float*    hB  = ws + H;
    unsigned* cnt = (unsigned*)(ws + 2 * H);   // monotonic arrival counter

    // ---- one-time load: pin weights on-chip ----
    const float4* w0p = (const float4*)(Whm + (size_t)r0 * H);
    const float4* w1p = (const float4*)(Whm + (size_t)r1 * H);
    const float4* u0p = (const float4*)(uWh + (size_t)r0 * H);
    const float4* u1p = (const float4*)(uWh + (size_t)r1 * H);
    const float4* p0p = (const float4*)(rWh + (size_t)r0 * H);
    const float4* p1p = (const float4*)(rWh + (size_t)r1 * H);

    float4 wA[J], wB[J];
    uint2  uA[J], uB[J];
    uint2* rs0 = rW + (wv * RPW + 0) * (H / 4);
    uint2* rs1 = rW + (wv * RPW + 1) * (H / 4);

#pragma unroll
    for (int j = 0; j < J; ++j) {
        const int idx = j * 64 + lane;
        wA[j] = w0p[idx];
        wB[j] = w1p[idx];
        uA[j] = pack4(u0p[idx]);
        uB[j] = pack4(u1p[idx]);
        rs0[idx] = pack4(p0p[idx]);
        rs1[idx] = pack4(p1p[idx]);
    }
#pragma unroll
    for (int j = 0; j < J; ++j) {
        asm volatile("" : "+v"(wA[j].x), "+v"(wA[j].y), "+v"(wA[j].z), "+v"(wA[j].w));
        asm volatile("" : "+v"(wB[j].x), "+v"(wB[j].y), "+v"(wB[j].z), "+v"(wB[j].w));
        asm volatile("" : "+v"(uA[j].x), "+v"(uA[j].y));
        asm volatile("" : "+v"(uB[j].x), "+v"(uB[j].y));
    }

    const float uwx0 = uWx[r0], uwx1 = uWx[r1], ub0 = ubv[r0], ub1 = ubv[r1];
    const float rwx0 = rWx[r0], rwx1 = rWx[r1], rb0 = rbv[r0], rb1 = rbv[r1];
    const float wx0  = wxv[r0], wx1  = wxv[r1], bb0 = bbv[r0], bb1 = bbv[r1];
    const float c0 = cv[0];

    // h0 = 0 (own 16 entries, straight to L3) + zero the arrival counter.
    if (tid < NELEM) store_l3_f32(&hA[bid * NELEM + tid], 0.f);
    if (bid == 0 && tid == 0) store_l3_u32(cnt, 0u);

    grid.sync();   // one-time: publishes zeros + counter before dataflow starts

    const float4* v4g = (const float4*)Vv;

#pragma unroll 1
    for (int t = 0; t < TOTAL; ++t) {
        const float4* hin4 = (const float4*)((t & 1) ? hB : hA);
        float*        hout = (t & 1) ? hA : hB;

        // ---- pull h_t from L3 into LDS ----
        float4 s0 = load_l3_f4(&hin4[tid]);
        float4 s1 = load_l3_f4(&hin4[tid + NTHR]);
        vm_drain();
        ((float4*)hF)[tid]        = s0;
        ((float4*)hF)[tid + NTHR] = s1;
        __syncthreads();

        float x;
        if (t < SEQ) {
            x = xseq[t];
        } else {
            // y = v.h + c0, redundantly and identically in every block
            float4 a0 = ((const float4*)hF)[tid];
            float4 a1 = ((const float4*)hF)[tid + NTHR];
            float p = dot4(a0, v4g[tid]) + dot4(a1, v4g[tid + NTHR]);
            p = wave_reduce(p);
            if (lane == 0) red[wv] = p;
            __syncthreads();
            float y = c0;
#pragma unroll
            for (int w = 0; w < NWAVE; ++w) y += red[w];
            x = y;
            if (t > SEQ && bid == 0 && tid == 0) out[t - SEQ - 1] = y;
        }

        // ---- six resident row-dots against LDS h ----
        float au0 = 0.f, au1 = 0.f, ar0 = 0.f, ar1 = 0.f, aw0 = 0.f, aw1 = 0.f;
#pragma unroll
        for (int j = 0; j < J; ++j) {
            const int idx = j * 64 + lane;
            const float4 hv = ((const float4*)hF)[idx];
            aw0 = fmaf(wA[j].x, hv.x, aw0); aw0 = fmaf(wA[j].y, hv.y, aw0);
            aw0 = fmaf(wA[j].z, hv.z, aw0); aw0 = fmaf(wA[j].w, hv.w, aw0);
            aw1 = fmaf(wB[j].x, hv.x, aw1); aw1 = fmaf(wB[j].y, hv.y, aw1);
            aw1 = fmaf(wB[j].z, hv.z, aw1); aw1 = fmaf(wB[j].w, hv.w, aw1);
            const float4 ua = unpack4(uA[j]);
            au0 = fmaf(ua.x, hv.x, au0); au0 = fmaf(ua.y, hv.y, au0);
            au0 = fmaf(ua.z, hv.z, au0); au0 = fmaf(ua.w, hv.w, au0);
            const float4 ub = unpack4(uB[j]);
            au1 = fmaf(ub.x, hv.x, au1); au1 = fmaf(ub.y, hv.y, au1);
            au1 = fmaf(ub.z, hv.z, au1); au1 = fmaf(ub.w, hv.w, au1);
            const float4 ra = unpack4(rs0[idx]);
            ar0 = fmaf(ra.x, hv.x, ar0); ar0 = fmaf(ra.y, hv.y, ar0);
            ar0 = fmaf(ra.z, hv.z, ar0); ar0 = fmaf(ra.w, hv.w, ar0);
            const float4 rb = unpack4(rs1[idx]);
            ar1 = fmaf(rb.x, hv.x, ar1); ar1 = fmaf(rb.y, hv.y, ar1);
            ar1 = fmaf(rb.z, hv.z, ar1); ar1 = fmaf(rb.w, hv.w, ar1);
        }
        au0 = wave_reduce(au0); au1 = wave_reduce(au1);
        ar0 = wave_reduce(ar0); ar1 = wave_reduce(ar1);
        aw0 = wave_reduce(aw0); aw1 = wave_reduce(aw1);

        if (lane == 0) {
            const float ho0 = hF[r0], ho1 = hF[r1];
            const float zu0 = fmaf(uwx0, x, au0 + ub0);
            const float zr0 = fmaf(rwx0, x, ar0 + rb0);
            const float u0  = 1.f / (1.f + expf(-zu0));
            const float g0  = 1.f / (1.f + expf(-zr0));
            const float hh0 = tanhf(fmaf(wx0, x, fmaf(g0, aw0, bb0)));
            store_l3_f32(&hout[r0], fmaf(u0, hh0 - ho0, ho0));
            const float zu1 = fmaf(uwx1, x, au1 + ub1);
            const float zr1 = fmaf(rwx1, x, ar1 + rb1);
            const float u1  = 1.f / (1.f + expf(-zu1));
            const float g1  = 1.f / (1.f + expf(-zr1));
            const float hh1 = tanhf(fmaf(wx1, x, fmaf(g1, aw1, bb1)));
            store_l3_f32(&hout[r1], fmaf(u1, hh1 - ho1, ho1));
        }
        // each wave drains its own h stores (vmcnt ack = visible at L3),
        // then the block-wide barrier orders all waves before the arrival add.
        vm_drain();
        __syncthreads();

        // ---- single-counter grid barrier: 1 atomic + 1 poller per block ----
        if (tid == 0) {
            __hip_atomic_fetch_add(cnt, 1u, __ATOMIC_RELAXED, AGENT);
            const unsigned target = (unsigned)(t + 1) * NBLK;
            while (load_l3_u32(cnt) < target)
                __builtin_amdgcn_s_sleep(2);
        }
        __syncthreads();   // release whole block; also protects hF reuse
    }

    // preds[63] from final h (t=TOTAL-1 odd -> hout was hA). The last barrier
    // already proved every block stored its final h.
    if (bid == 0) {
        float4 s0 = load_l3_f4(&((const float4*)hA)[tid]);
        float4 s1 = load_l3_f4(&((const float4*)hA)[tid + NTHR]);
        vm_drain();
        ((float4*)hF)[tid]        = s0;
        ((float4*)hF)[tid + NTHR] = s1;
        __syncthreads();
        float4 a0 = ((const float4*)hF)[tid];
        float4 a1 = ((const float4*)hF)[tid + NTHR];
        float p = dot4(a0, v4g[tid]) + dot4(a1, v4g[tid + NTHR]);
        p = wave_reduce(p);
        if (lane == 0) red[wv] = p;
        __syncthreads();
        if (tid == 0) {
            float y = c0;
            for (int w = 0; w < NWAVE; ++w) y += red[w];
            out[HOR - 1] = y;
        }
    }
}

extern "C" void kernel_launch(void* const* d_in, const int* in_sizes, int n_in,
                              void* d_out, int out_size, void* d_ws, size_t ws_size,
                              hipStream_t stream) {
    const float* xseq = (const float*)d_in[0];
    const float* uWx  = (const float*)d_in[2];
    const float* uWh  = (const float*)d_in[3];
    const float* ubv  = (const float*)d_in[4];
    const float* rWx  = (const float*)d_in[5];
    const float* rWh  = (const float*)d_in[6];
    const float* rbv  = (const float*)d_in[7];
    const float* wxv  = (const float*)d_in[8];
    const float* Whm  = (const float*)d_in[9];
    const float* bbv  = (const float*)d_in[10];
    const float* Vv   = (const float*)d_in[11];
    const float* cv   = (const float*)d_in[12];
    float* out = (float*)d_out;
    float* ws  = (float*)d_ws;

    (void)hipFuncSetAttribute((const void*)gru_kernel,
                        hipFuncAttributeMaxDynamicSharedMemorySize, SMEM_BYTES);

    void* args[] = { &xseq, &uWx, &uWh, &ubv, &rWx, &rWh, &rbv,
                     &wxv, &Whm, &bbv, &Vv, &cv, &out, &ws };
    (void)hipLaunchCooperativeKernel((void*)gru_kernel, dim3(NBLK), dim3(NTHR),
                               args, SMEM_BYTES, stream);
}